// Round 6
// baseline (43.968 us; speedup 1.0000x reference)
//
#include <hip/hip_runtime.h>

// Implicit-GEMM MFMA conv, round 6: single fused conv (inline f32->bf16
// staging, no xb pass) + tiny 19-block kw precompute.
//  - prep_k: K' (19 non-corner taps, sc folded into center tap) -> bf16
//    B-frags in d_ws (77824 B).
//  - conv_fused: Yg=8 tile (LDS 65280B, 2 blk/CU), reg-staged f32->bf16 with
//    XOR-swizzled LDS layout, M=64/wave, depth-3 prefetch into size-4 B-frag
//    register ring, batched A ds_reads, pad-only zeroing, XCD-aware bid swizzle.

typedef __attribute__((ext_vector_type(8))) short bf16x8;
typedef __attribute__((ext_vector_type(4))) float f32x4;
typedef unsigned int u32;

__device__ __forceinline__ float sus_f(float v) { return v > 0.f ? __expf(-1.f / v) : 0.f; }

__device__ __forceinline__ unsigned short f2bf(float f) {
    union { float f; unsigned u; } c; c.f = f;
    unsigned u = c.u;
    u += 0x7FFFu + ((u >> 16) & 1u);          // round-to-nearest-even
    return (unsigned short)(u >> 16);
}

// ---------------- kw precompute: 19 blocks x 256 threads ----------------
// kw layout (bf16): frag[ta][nt][lane=64][slot=8]
//   value = K[t][ci = 8*(lane>>4) + slot][o = 16*nt + (lane&15)]
__global__ __launch_bounds__(256) void prep_k(
    const float* __restrict__ w_lin0, const float* __restrict__ w_lin1,
    const float* __restrict__ w000,  const float* __restrict__ w011,
    const float* __restrict__ w101,  const float* __restrict__ w110,
    unsigned short* __restrict__ kw)
{
    const int taps[19] = {1,3,4,5,7,9,10,11,12,13,14,15,16,17,19,21,22,23,25};
    const int ta = blockIdx.x;
    const int t = taps[ta];
    const int a = t / 9, b = (t / 3) % 3, c = t % 3;

    const float fx = (float)(a - 1), fy = (float)(b - 1), fz = (float)(c - 1);
    const float dist = sqrtf(fx * fx + fy * fy + fz * fz);
    float emb[4];
    #pragma unroll
    for (int r = 0; r < 4; ++r) {
        const float v = 0.3f * (float)(r + 1);
        const float d = (dist - v) * (1.0f / 0.3f);
        emb[r] = 8.4335731f * sus_f(d + 1.f) * sus_f(1.f - d);
    }
    const float s = (dist > 0.f) ? (1.7320508f / dist) : 0.f;
    const float shv[3] = { fx * s, fy * s, fz * s };
    const float S000 = 0.25f / 27.f;
    const float S1   = 0.25f * 0.57735027f / 27.f;
    const float LNRM = 0.35355339f;

    const int tid = threadIdx.x;
    const int ci = tid >> 3;
    #pragma unroll
    for (int j = 0; j < 8; ++j) {
        const int o = (tid & 7) * 8 + j;
        float val;
        if (ci < 8) {
            const int u = ci;
            if (o < 16) {
                const float* p = w000 + u * 16 + o;
                val = S000 * (emb[0]*p[0] + emb[1]*p[128] + emb[2]*p[256] + emb[3]*p[384]);
                if (t == 13) val += LNRM * w_lin0[u * 16 + o];
            } else {
                const int oo = o - 16, w = oo / 3, m = oo % 3;
                const float* p = w011 + u * 16 + w;
                val = S1 * shv[m] * (emb[0]*p[0] + emb[1]*p[128] + emb[2]*p[256] + emb[3]*p[384]);
            }
        } else {
            const int iu = ci - 8, u = iu / 3, ic = iu % 3;
            if (o < 16) {
                const float* p = w110 + u * 16 + o;
                val = S1 * shv[ic] * (emb[0]*p[0] + emb[1]*p[128] + emb[2]*p[256] + emb[3]*p[384]);
            } else {
                const int oo = o - 16, w = oo / 3, m = oo % 3;
                if (ic == m) {
                    const float* p = w101 + u * 16 + w;
                    val = S1 * (emb[0]*p[0] + emb[1]*p[128] + emb[2]*p[256] + emb[3]*p[384]);
                    if (t == 13) val += LNRM * w_lin1[u * 16 + w];
                } else {
                    val = 0.f;
                }
            }
        }
        const int g = ci >> 3, slot = ci & 7, nt = o >> 4, cc = o & 15;
        const int lane = (g << 4) | cc;
        kw[((size_t)(ta * 4 + nt) * 64 + lane) * 8 + slot] = f2bf(val);
    }
}

// ---------------- fused conv kernel ----------------
// LDS tile: [dx=3][y10=10][zp=34][ci=32] bf16 (zp 0/33 are zero pads), 65280 B.
// Within a (dx,y10,zp) row, 16B ci-groups stored at slot ^ ((zp>>1)&3).
__global__ __launch_bounds__(256, 2) void conv_fused(
    const float* __restrict__ x,
    const unsigned short* __restrict__ kw,
    float* __restrict__ out)
{
    __shared__ unsigned short lx[3 * 10 * 34 * 32];   // 65280 B

    const int tid = threadIdx.x;
    const int bid = blockIdx.x;
    // XCD swizzle: bid&7 = XCD; each XCD owns one batch n, X sweeping sequentially.
    const int xcd = bid & 7, idx = bid >> 3;
    const int gid = xcd * 128 + idx;
    const int n = gid >> 7, X = (gid >> 2) & 31, Yg = gid & 3;
    const int Y0 = Yg * 8;
    const int wid = tid >> 6, l = tid & 63, lr = l & 15, lg = l >> 4;

    const bf16x8* kwf = reinterpret_cast<const bf16x8*>(kw);

    // ---- B-frag ring preload (taps 0..2 into slots 0..2); slot ta&3 consumed
    // at iter ta, slot (ta+3)&3 refilled at iter ta -> never aliases.
    bf16x8 bring[4][4];
    #pragma unroll
    for (int p = 0; p < 3; ++p)
        #pragma unroll
        for (int nt = 0; nt < 4; ++nt)
            bring[p][nt] = kwf[(size_t)(p * 4 + nt) * 64 + l];

    // ---- zero pad slots only (zp=0 and zp=33 of each of the 30 rows) ----
    if (tid < 60) {
        const int row = tid >> 1, zp = (tid & 1) * 33;
        f32x4* dp = reinterpret_cast<f32x4*>(
            reinterpret_cast<char*>(lx) + row * 2176 + zp * 64);
        #pragma unroll
        for (int q = 0; q < 4; ++q) dp[q] = (f32x4)0.f;
    }

    // ---- staging: f32 -> bf16 in-kernel, swizzled ds_writes ----
    // 960 items = 30 rows x 32 z; item -> (dx, y6, z)
    for (int it = tid; it < 960; it += 256) {
        const int dx = it / 320, rem = it - dx * 320;
        const int y6 = rem >> 5, z = rem & 31;
        const int gx = X + dx - 1, gy = Y0 + y6 - 1;
        char* row = reinterpret_cast<char*>(lx) + (dx * 10 + y6) * 2176 + (z + 1) * 64;
        if ((unsigned)gx < 32u && (unsigned)gy < 32u) {
            const float4* sp = reinterpret_cast<const float4*>(
                x + ((size_t)(((n * 32 + gx) * 32 + gy) * 32 + z) << 5));
            const int swz = ((z + 1) >> 1) & 3;
            #pragma unroll
            for (int g = 0; g < 4; ++g) {
                const float4 lo = sp[2 * g], hi = sp[2 * g + 1];
                bf16x8 w;
                w[0] = (short)f2bf(lo.x); w[1] = (short)f2bf(lo.y);
                w[2] = (short)f2bf(lo.z); w[3] = (short)f2bf(lo.w);
                w[4] = (short)f2bf(hi.x); w[5] = (short)f2bf(hi.y);
                w[6] = (short)f2bf(hi.z); w[7] = (short)f2bf(hi.w);
                *reinterpret_cast<bf16x8*>(row + ((g ^ swz) << 4)) = w;
            }
        } else {
            bf16x8 zz = (bf16x8)(short)0;
            #pragma unroll
            for (int g = 0; g < 4; ++g)
                *reinterpret_cast<bf16x8*>(row + (g << 4)) = zz;
        }
    }
    __syncthreads();

    // ---- barrier-free tap loop; wave owns y-pair (Y0+2*wid, +1), M=64 ----
    constexpr int TA[19] = {1,3,4,5,7,9,10,11,12,13,14,15,16,17,19,21,22,23,25};
    const char* lxc = reinterpret_cast<const char*>(lx);
    const int yloc = wid * 2;

    f32x4 acc[4][4];
    #pragma unroll
    for (int r = 0; r < 4; ++r)
        #pragma unroll
        for (int nt = 0; nt < 4; ++nt) acc[r][nt] = (f32x4)0.f;

    #pragma unroll
    for (int ta = 0; ta < 19; ++ta) {
        const int t = TA[ta];
        const int a = t / 9, b = (t / 3) % 3, c = t % 3;

        // refill ring slot (ta+3)&3 (static index after unroll; != consumed ta&3)
        if (ta + 3 < 19) {
            #pragma unroll
            for (int nt = 0; nt < 4; ++nt)
                bring[(ta + 3) & 3][nt] = kwf[(size_t)((ta + 3) * 4 + nt) * 64 + l];
        }

        // batched A-fragment reads (one lgkm group)
        bf16x8 af[4];
        #pragma unroll
        for (int r = 0; r < 4; ++r) {
            const int y10 = yloc + (r >> 1) + b;
            const int zp = 16 * (r & 1) + lr + c;
            const int byte = ((a * 10 + y10) * 34 + zp) * 64 + ((lg ^ ((zp >> 1) & 3)) << 4);
            af[r] = *reinterpret_cast<const bf16x8*>(lxc + byte);
        }

        #pragma unroll
        for (int r = 0; r < 4; ++r)
            #pragma unroll
            for (int nt = 0; nt < 4; ++nt)
                acc[r][nt] = __builtin_amdgcn_mfma_f32_16x16x32_bf16(
                    af[r], bring[ta & 3][nt], acc[r][nt], 0, 0, 0);
    }

    // ---- epilogue: C col = lane&15 (out-ch), row = (lane>>4)*4 + reg (z) ----
    float* ob = out + ((size_t)(((n * 32 + X) * 32 + Y0 + yloc) * 32) << 6);
    #pragma unroll
    for (int r = 0; r < 4; ++r) {
        float* oy = ob + (size_t)(r >> 1) * 2048;
        #pragma unroll
        for (int nt = 0; nt < 4; ++nt)
            #pragma unroll
            for (int reg = 0; reg < 4; ++reg) {
                const int z = 16 * (r & 1) + 4 * lg + reg;
                oy[z * 64 + nt * 16 + lr] = acc[r][nt][reg];
            }
    }
}

extern "C" void kernel_launch(void* const* d_in, const int* in_sizes, int n_in,
                              void* d_out, int out_size, void* d_ws, size_t ws_size,
                              hipStream_t stream) {
    const float* x    = (const float*)d_in[0];
    const float* wl0  = (const float*)d_in[1];
    const float* wl1  = (const float*)d_in[2];
    const float* w000 = (const float*)d_in[3];
    const float* w011 = (const float*)d_in[4];
    const float* w101 = (const float*)d_in[5];
    const float* w110 = (const float*)d_in[6];
    float* out = (float*)d_out;
    unsigned short* kw = (unsigned short*)d_ws;   // 77824 B

    prep_k<<<dim3(19), dim3(256), 0, stream>>>(wl0, wl1, w000, w011, w101, w110, kw);
    conv_fused<<<dim3(1024), dim3(256), 0, stream>>>(x, kw, out);
}